// Round 20
// baseline (331.102 us; speedup 1.0000x reference)
//
#include <hip/hip_runtime.h>
#include <cstdint>

typedef unsigned short u16;
typedef __attribute__((ext_vector_type(8))) short bf16x8;
typedef __attribute__((ext_vector_type(4))) float f32x4;

#define S_LEN 2048
#define DM    2048
#define NH    16
#define HDIM  128

__device__ __forceinline__ u16 f2bf(float f) {
  union { float f; unsigned u; } v; v.f = f;
  unsigned r = v.u + 0x7fffu + ((v.u >> 16) & 1u);
  return (u16)(r >> 16);
}
__device__ __forceinline__ float bf2f(u16 h) {
  union { unsigned u; float f; } v; v.u = ((unsigned)h) << 16;
  return v.f;
}

typedef __attribute__((address_space(3))) void lds_void_t;
typedef const __attribute__((address_space(1))) void gbl_void_t;
__device__ __forceinline__ void gload_lds16(const void* g, void* l) {
  __builtin_amdgcn_global_load_lds((gbl_void_t*)g, (lds_void_t*)l, 16, 0, 0);
}

#define VMCNTN(nn) asm volatile("s_waitcnt vmcnt(%0)" :: "n"(nn) : "memory")
#define LGKMCNT0() asm volatile("s_waitcnt lgkmcnt(0)" ::: "memory")

// ---------------------------------------------------------------- convert (5 tensors, one launch)
__global__ void cvt5_k(const float* s0, u16* d0, int n0,
                       const float* s1, u16* d1, int n1,
                       const float* s2, u16* d2, int n2,
                       const float* s3, u16* d3, int n3,
                       const float* s4, u16* d4, int n4) {
  const int stride = gridDim.x * blockDim.x;
  const int tid = blockIdx.x * blockDim.x + threadIdx.x;
#define CVT(S, D, N)                                        \
  for (int i = tid; i < ((N) >> 2); i += stride) {          \
    float4 v = ((const float4*)(S))[i];                     \
    ushort4 o;                                              \
    o.x = f2bf(v.x); o.y = f2bf(v.y);                       \
    o.z = f2bf(v.z); o.w = f2bf(v.w);                       \
    ((ushort4*)(D))[i] = o;                                 \
  }
  CVT(s0, d0, n0) CVT(s1, d1, n1) CVT(s2, d2, n2)
  CVT(s3, d3, n3) CVT(s4, d4, n4)
#undef CVT
}

// ---------------------------------------------------------------- half-tile dbuf GEMM + T2 slot-swizzle  [R18]
template <int BM, int BN, int M, int N, int K, typename CT, int MODE>
__global__ __launch_bounds__(512, 2) void gemm8(const u16* __restrict__ A,
                                                const u16* __restrict__ Bm,
                                                CT* __restrict__ C,
                                                const float* __restrict__ fc,
                                                const float* __restrict__ fs,
                                                u16* __restrict__ qtp,
                                                u16* __restrict__ ktp) {
  constexpr int PWM = BM / 2, PWN = BN / 4;
  constexpr int MR = PWM / 16, NR = PWN / 16;
  constexpr int LA = BM / 128, LB = BN / 128;
  constexpr int VMK = LA + LB;
  constexpr int LDSA = BM * 32, LDSB = BN * 32;
  constexpr int nbn = N / BN, nbm = M / BM;
  constexpr int nwg = nbm * nbn;                 // must be % 8 == 0
  constexpr int GM = 8;
  __shared__ u16 sA[2 * LDSA];
  __shared__ u16 sB[2 * LDSB];

  const int t = threadIdx.x;
  const int lane = t & 63, wid = t >> 6;
  const int r0 = lane & 15, kq = lane >> 4;
  const int wr = wid >> 2, wc = wid & 3;

  const int bid = blockIdx.x;
  const int wgl = (bid & 7) * (nwg >> 3) + (bid >> 3);  // XCD-contiguous
  const int gid = wgl / (GM * nbn);
  const int rem = wgl % (GM * nbn);
  const long tile_m = (long)(gid * GM + (rem & (GM - 1))) * BM;
  const long tile_n = (long)(rem >> 3) * BN;

  constexpr int NPH = K / 32;                    // half-tile phases

  const int swzcol = ((t & 3) ^ ((t >> 3) & 3)) * 8;
  const u16* gA = A + (tile_m + (t >> 2)) * (long)K + swzcol;
  const u16* gB = Bm + (tile_n + (t >> 2)) * (long)K + swzcol;

  auto stage = [&](int h) {
    u16* ba = &sA[(h & 1) * LDSA] + wid * 512;
    u16* bb = &sB[(h & 1) * LDSB] + wid * 512;
    const long coff = (long)h * 32;
#pragma unroll
    for (int r = 0; r < LA; ++r)
      gload_lds16(gA + (long)(r * 128) * K + coff, ba + r * 4096);
#pragma unroll
    for (int r = 0; r < LB; ++r)
      gload_lds16(gB + (long)(r * 128) * K + coff, bb + r * 4096);
  };

  const int rdslot = (kq ^ ((r0 >> 1) & 3)) * 8;
  const int aoff = (wr * PWM + r0) * 32 + rdslot;
  const int boff = (wc * PWN + r0) * 32 + rdslot;

  f32x4 acc[MR][NR];
#pragma unroll
  for (int m = 0; m < MR; ++m)
#pragma unroll
    for (int n = 0; n < NR; ++n) acc[m][n] = (f32x4){0.f, 0.f, 0.f, 0.f};

  stage(0); stage(1);
  VMCNTN(VMK);
  __builtin_amdgcn_s_barrier();

  for (int h = 0; h < NPH; ++h) {
    const u16* ra = &sA[(h & 1) * LDSA] + aoff;
    const u16* rb = &sB[(h & 1) * LDSB] + boff;
    bf16x8 a[MR], b[NR];
#pragma unroll
    for (int m = 0; m < MR; ++m) a[m] = *(const bf16x8*)(ra + m * 512);
#pragma unroll
    for (int n = 0; n < NR; ++n) b[n] = *(const bf16x8*)(rb + n * 512);
    LGKMCNT0();
    __builtin_amdgcn_s_barrier();
    stage(h + 2);
    __builtin_amdgcn_s_setprio(1);
#pragma unroll
    for (int m = 0; m < MR; ++m)
#pragma unroll
      for (int n = 0; n < NR; ++n)
        acc[m][n] = __builtin_amdgcn_mfma_f32_16x16x32_bf16(a[m], b[n],
                                                            acc[m][n], 0, 0, 0);
    __builtin_amdgcn_s_setprio(0);
    VMCNTN(VMK);
    __builtin_amdgcn_s_barrier();
  }

  if constexpr (MODE == 1) {
    const int z = (int)(tile_n >> 11);         // 0=q 1=k 2=v (block-uniform)
    if (z == 2) {
#pragma unroll
      for (int m = 0; m < MR; ++m)
#pragma unroll
        for (int n = 0; n < NR; ++n)
#pragma unroll
          for (int r = 0; r < 4; ++r) {
            long grow = tile_m + wr * PWM + m * 16 + kq * 4 + r;
            long gcol = tile_n + wc * PWN + n * 16 + r0;
            C[grow * N + gcol] = (CT)f2bf(acc[m][n][r]);
          }
    } else {
      const float qsc = 0.12751743202f;        // log2(e)/sqrt(128)
#pragma unroll
      for (int m = 0; m < MR; ++m)
#pragma unroll
        for (int n = 0; n < NR; ++n)
#pragma unroll
          for (int r = 0; r < 4; ++r) {
            long grow = tile_m + wr * PWM + m * 16 + kq * 4 + r;
            long gcol = tile_n + wc * PWN + n * 16 + r0;
            int srow = (int)(grow & 2047), bidx = (int)(grow >> 11);
            int h = ((int)gcol >> 7) & 15, hd = (int)gcol & 127;
            float v = acc[m][n][r];
            float partner = __shfl_xor(v, 1);
            int hd2 = hd >> 1;
            float c = fc[srow * 64 + hd2], sn = fs[srow * 64 + hd2];
            float res = (r0 & 1) ? (partner * sn + v * c)
                                 : (v * c - partner * sn);
            if (z == 0) res *= qsc;
            u16* dst = z ? ktp : qtp;
            dst[((long)(bidx * 16 + h) * S_LEN + srow) * HDIM + hd] = f2bf(res);
          }
    }
  } else {
#pragma unroll
    for (int m = 0; m < MR; ++m)
#pragma unroll
      for (int n = 0; n < NR; ++n)
#pragma unroll
        for (int r = 0; r < 4; ++r) {
          long grow = tile_m + wr * PWM + m * 16 + kq * 4 + r;
          long gcol = tile_n + wc * PWN + n * 16 + r0;
          float v = acc[m][n][r];
          if constexpr (sizeof(CT) == 2) C[grow * N + gcol] = (CT)f2bf(v);
          else                           C[grow * N + gcol] = v;
        }
  }
}

// ---------------------------------------------------------------- V transpose -> (B,H,HD,S)
__global__ void vtrans_k(const u16* __restrict__ qkv, u16* __restrict__ vt) {
  __shared__ u16 tile[64][65];
  int bh = blockIdx.z;
  int b = bh >> 4, h = bh & 15;
  int s0 = blockIdx.x * 64, d0 = blockIdx.y * 64;
  int tx = threadIdx.x, ty = threadIdx.y;
#pragma unroll
  for (int i = 0; i < 64; i += 4) {
    int s = s0 + ty + i;
    tile[ty + i][tx] = qkv[((long)(b * S_LEN + s)) * 6144 + 4096 + h * HDIM + d0 + tx];
  }
  __syncthreads();
#pragma unroll
  for (int i = 0; i < 64; i += 4) {
    int d = d0 + ty + i;
    vt[((long)bh * HDIM + d) * S_LEN + s0 + tx] = tile[tx][ty + i];
  }
}

// ---------------------------------------------------------------- flash attention v12: split-KV partials
// Each 32-row segment's KV range [0, (seg+1)*32) split into 2 balanced chunks
// (grid z). Critical path 64 -> ~33 steps (R19: flash was critical-path-bound,
// avg waves/CU = 66560/(256*64) = 4.06 = measured). Partials: unnormalized O
// (bf16) + per-row (m,l) f32; comb_k merges. Same per-XCD bh mapping.
__global__ __launch_bounds__(64) void flash_k(const u16* __restrict__ qt,
                                              const u16* __restrict__ kt,
                                              const u16* __restrict__ vt,
                                              u16* __restrict__ op0,
                                              u16* __restrict__ op1,
                                              float* __restrict__ ml) {
  constexpr int PS = 40;
  __shared__ u16 pbuf[2][32 * PS];   // [parity]
  const int lane = threadIdx.x & 63;
  const int r0 = lane & 15, kq = lane >> 4;
  const int bh = blockIdx.x;
  const int seg = (gridDim.y - 1) - blockIdx.y;    // heavy-first
  const int chunk = blockIdx.z;
  const int q0w = seg * 32;
  const int crow = kq * 4;

  const int nst = seg + 1;                         // total kv steps
  const int beg = chunk ? (nst >> 1) : 0;
  const int endst = chunk ? nst : (nst >> 1);
  const int kbeg = beg * 32;
  const int lastkv = (endst - 1) * 32;             // valid only if endst>beg

  const u16* qb = qt + ((long)bh * S_LEN + q0w) * HDIM;
  const u16* kb = kt + (long)bh * S_LEN * HDIM;
  const u16* vb = vt + (long)bh * HDIM * S_LEN;
  u16* pb0 = &pbuf[0][0];
  u16* pb1 = &pbuf[1][0];

  bf16x8 aq[2][4];
#pragma unroll
  for (int qc = 0; qc < 2; ++qc)
#pragma unroll
    for (int kk = 0; kk < 4; ++kk)
      aq[qc][kk] = *(const bf16x8*)(qb + (qc * 16 + r0) * HDIM + kk * 32 + kq * 8);

  f32x4 o[2][8];
  float mrow[2] = {-1e30f, -1e30f}, lrow[2] = {0.f, 0.f};
#pragma unroll
  for (int qc = 0; qc < 2; ++qc)
#pragma unroll
    for (int dt = 0; dt < 8; ++dt) o[qc][dt] = (f32x4){0.f, 0.f, 0.f, 0.f};

  bf16x8 bkA[2][4], bkB[2][4], bvA[8], bvB[8];
  f32x4 saccA[2][2], saccB[2][2];

  auto loadK = [&](bf16x8 (&dst)[2][4], int kv) {
#pragma unroll
    for (int kc = 0; kc < 2; ++kc)
#pragma unroll
      for (int kk = 0; kk < 4; ++kk)
        dst[kc][kk] = *(const bf16x8*)(kb + (long)(kv + kc * 16 + r0) * HDIM + kk * 32 + kq * 8);
  };
  auto loadV = [&](bf16x8 (&dst)[8], int kv) {
#pragma unroll
    for (int dt = 0; dt < 8; ++dt)
      dst[dt] = *(const bf16x8*)(vb + (long)(dt * 16 + r0) * S_LEN + kv + kq * 8);
  };
  auto qk = [&](bf16x8 (&kf)[2][4], f32x4 (&sacc)[2][2]) {
    __builtin_amdgcn_s_setprio(1);
#pragma unroll
    for (int kc = 0; kc < 2; ++kc) {
      f32x4 a0 = (f32x4){0.f, 0.f, 0.f, 0.f};
      f32x4 a1 = (f32x4){0.f, 0.f, 0.f, 0.f};
#pragma unroll
      for (int kk = 0; kk < 4; ++kk) {
        a0 = __builtin_amdgcn_mfma_f32_16x16x32_bf16(kf[kc][kk], aq[0][kk], a0, 0, 0, 0);
        a1 = __builtin_amdgcn_mfma_f32_16x16x32_bf16(kf[kc][kk], aq[1][kk], a1, 0, 0, 0);
      }
      sacc[kc][0] = a0; sacc[kc][1] = a1;
    }
    __builtin_amdgcn_s_setprio(0);
  };
  auto softmax_store = [&](f32x4 (&sacc)[2][2], int kv0, u16* pb) {
    const bool diag = (kv0 == q0w);
#pragma unroll
    for (int qc = 0; qc < 2; ++qc) {
      float s[2][4];
#pragma unroll
      for (int kc = 0; kc < 2; ++kc)
#pragma unroll
        for (int r = 0; r < 4; ++r) {
          float v = sacc[kc][qc][r];
          if (diag && (kc * 16 + crow + r > qc * 16 + r0)) v = -1e30f;
          s[kc][r] = v;
        }
      float pm = fmaxf(fmaxf(fmaxf(s[0][0], s[0][1]), fmaxf(s[0][2], s[0][3])),
                       fmaxf(fmaxf(s[1][0], s[1][1]), fmaxf(s[1][2], s[1][3])));
      pm = fmaxf(pm, __shfl_xor(pm, 16));
      pm = fmaxf(pm, __shfl_xor(pm, 32));
      if (!__all(pm - mrow[qc] <= 11.5416f)) {   // defer-max (log2 units, e^8 bound)
        float mnew = fmaxf(mrow[qc], pm);
        float co = exp2f(mrow[qc] - mnew);
        mrow[qc] = mnew;
        lrow[qc] *= co;
        float cod[4];
#pragma unroll
        for (int r = 0; r < 4; ++r)
          cod[r] = __shfl(co, (lane & 48) | (crow + r));
#pragma unroll
        for (int dt = 0; dt < 8; ++dt)
#pragma unroll
          for (int r = 0; r < 4; ++r)
            o[qc][dt][r] *= cod[r];
      }
      float p[2][4];
      float rs = 0.f;
#pragma unroll
      for (int kc = 0; kc < 2; ++kc)
#pragma unroll
        for (int r = 0; r < 4; ++r) {
          p[kc][r] = exp2f(s[kc][r] - mrow[qc]);
          rs += p[kc][r];
        }
      rs += __shfl_xor(rs, 16);
      rs += __shfl_xor(rs, 32);
      lrow[qc] += rs;
#pragma unroll
      for (int kc = 0; kc < 2; ++kc) {
        unsigned w0, w1;
        asm("v_cvt_pk_bf16_f32 %0, %1, %2" : "=v"(w0) : "v"(p[kc][0]), "v"(p[kc][1]));
        asm("v_cvt_pk_bf16_f32 %0, %1, %2" : "=v"(w1) : "v"(p[kc][2]), "v"(p[kc][3]));
        uint2 w; w.x = w0; w.y = w1;
        *(uint2*)(pb + (qc * 16 + r0) * PS + kc * 16 + crow) = w;
      }
    }
  };
  auto pv = [&](const u16* pb, bf16x8 (&bv)[8]) {
    bf16x8 pa0 = *(const bf16x8*)(pb + r0 * PS + kq * 8);
    bf16x8 pa1 = *(const bf16x8*)(pb + (16 + r0) * PS + kq * 8);
    __builtin_amdgcn_s_setprio(1);
#pragma unroll
    for (int dt = 0; dt < 8; ++dt) {
      o[0][dt] = __builtin_amdgcn_mfma_f32_16x16x32_bf16(pa0, bv[dt], o[0][dt], 0, 0, 0);
      o[1][dt] = __builtin_amdgcn_mfma_f32_16x16x32_bf16(pa1, bv[dt], o[1][dt], 0, 0, 0);
    }
    __builtin_amdgcn_s_setprio(0);
  };

  if (endst > beg) {
    loadK(bkA, kbeg);
    if (kbeg + 32 <= lastkv) loadK(bkB, kbeg + 32);
    qk(bkA, saccA);
    int kv0 = kbeg;
    for (;;) {
      {
        const bool more = (kv0 + 32 <= lastkv);
        loadV(bvA, kv0);
        softmax_store(saccA, kv0, pb0);
        if (more) qk(bkB, saccB);
        if (kv0 + 64 <= lastkv) loadK(bkA, kv0 + 64);
        pv(pb0, bvA);
        kv0 += 32;
        if (!more) break;
      }
      {
        const bool more = (kv0 + 32 <= lastkv);
        loadV(bvB, kv0);
        softmax_store(saccB, kv0, pb1);
        if (more) qk(bkA, saccA);
        if (kv0 + 64 <= lastkv) loadK(bkB, kv0 + 64);
        pv(pb1, bvB);
        kv0 += 32;
        if (!more) break;
      }
    }
  }

  // epilogue: write UNNORMALIZED partials + (m,l)
  u16* op = chunk ? op1 : op0;
#pragma unroll
  for (int qc = 0; qc < 2; ++qc)
#pragma unroll
    for (int dt = 0; dt < 8; ++dt)
#pragma unroll
      for (int r = 0; r < 4; ++r) {
        int srow = q0w + qc * 16 + crow + r;
        op[((long)bh * S_LEN + srow) * HDIM + dt * 16 + r0] = f2bf(o[qc][dt][r]);
      }
  if (kq == 0) {                      // lane r0 holds (m,l) for q row qc*16+r0
    float* mlp = ml + (long)chunk * (32 * S_LEN * 2);
#pragma unroll
    for (int qc = 0; qc < 2; ++qc) {
      long row = (long)bh * S_LEN + q0w + qc * 16 + r0;
      mlp[row * 2]     = mrow[qc];
      mlp[row * 2 + 1] = lrow[qc];
    }
  }
}

// ---------------------------------------------------------------- combine partials -> attn (B,S,D)
__global__ __launch_bounds__(256) void comb_k(const u16* __restrict__ op0,
                                              const u16* __restrict__ op1,
                                              const float* __restrict__ ml,
                                              u16* __restrict__ attn) {
  const long g = (long)blockIdx.x * 256 + threadIdx.x;   // 1,048,576 threads
  const long row = g >> 4;                                // bh*2048 + s
  const int c0 = (int)(g & 15) * 8;
  const int bh = (int)(row >> 11), s = (int)(row & 2047);
  const int b = bh >> 4, h = bh & 15;

  const float m0 = ml[row * 2], l0 = ml[row * 2 + 1];
  const float m1 = ml[32 * S_LEN * 2 + row * 2], l1 = ml[32 * S_LEN * 2 + row * 2 + 1];
  const float m = fmaxf(m0, m1);
  const float w0 = exp2f(m0 - m), w1 = exp2f(m1 - m);
  const float inv = 1.0f / (l0 * w0 + l1 * w1);

  bf16x8 a = *(const bf16x8*)(op0 + row * HDIM + c0);
  bf16x8 c = *(const bf16x8*)(op1 + row * HDIM + c0);
  ushort4 out[2];
#pragma unroll
  for (int j = 0; j < 8; ++j) {
    float v = (bf2f((u16)a[j]) * w0 + bf2f((u16)c[j]) * w1) * inv;
    ((u16*)out)[j] = f2bf(v);
  }
  *(ushort4*)(attn + ((long)(b * S_LEN + s)) * DM + h * HDIM + c0) = out[0];
  *(ushort4*)(attn + ((long)(b * S_LEN + s)) * DM + h * HDIM + c0 + 4) = out[1];
}

// ---------------------------------------------------------------- launch
extern "C" void kernel_launch(void* const* d_in, const int* in_sizes, int n_in,
                              void* d_out, int out_size, void* d_ws, size_t ws_size,
                              hipStream_t stream) {
  (void)in_sizes; (void)n_in; (void)out_size; (void)ws_size;
  const float* x  = (const float*)d_in[0];
  const float* fc = (const float*)d_in[2];
  const float* fs = (const float*)d_in[3];
  const float* wq = (const float*)d_in[5];
  const float* wk = (const float*)d_in[6];
  const float* wv = (const float*)d_in[7];
  const float* wo = (const float*)d_in[8];
  float* out = (float*)d_out;

  u16* xb   = (u16*)d_ws;            // 4096*2048
  u16* wqkv = xb + 8388608;          // 6144*2048
  u16* wob  = wqkv + 12582912;       // 2048*2048
  u16* qkv  = wob + 4194304;         // 4096*6144 (only v region written now)
  u16* qt   = qkv + 25165824;        // 32*2048*128
  u16* kt   = qt + 8388608;
  u16* vt   = kt + 8388608;
  u16* attn = qkv;                   // alias: v region dead after vtrans
  // split-KV partials reuse regions dead after the QKV GEMM:
  u16*   op0 = xb;                   // 32*2048*128 exactly
  u16*   op1 = wqkv;                 // first 8.4M of 12.6M
  float* ml  = (float*)(wqkv + 8388608);  // 2 chunks * 65536 rows * 2 f32 = 1MB

  cvt5_k<<<2048, 256, 0, stream>>>(x, xb, 8388608,
                                   wq, wqkv, 4194304,
                                   wk, wqkv + 4194304, 4194304,
                                   wv, wqkv + 8388608, 4194304,
                                   wo, wob, 4194304);

  // QKV: M=4096 N=6144 K=2048, BM=128 -> 768 blocks; 2 blocks/CU
  gemm8<128, 256, 4096, 6144, 2048, u16, 1><<<768, 512, 0, stream>>>(
      xb, wqkv, qkv, fc, fs, qt, kt);

  vtrans_k<<<dim3(32, 2, 32), dim3(64, 4), 0, stream>>>(qkv, vt);

  // split-KV flash: grid (bh, 64 segs heavy-first, 2 chunks) = 4096 blocks
  flash_k<<<dim3(32, 64, 2), 64, 0, stream>>>(qt, kt, vt, op0, op1, ml);

  // combine partials into attn (B,S,D)
  comb_k<<<4096, 256, 0, stream>>>(op0, op1, ml, attn);

  // OUT: M=4096 N=2048 K=2048, BM=128 -> 256 blocks
  gemm8<128, 256, 4096, 2048, 2048, float, 0><<<256, 512, 0, stream>>>(
      attn, wob, out, nullptr, nullptr, nullptr, nullptr);
}

// Round 21
// 317.468 us; speedup vs baseline: 1.0429x; 1.0429x over previous
//
#include <hip/hip_runtime.h>
#include <cstdint>

typedef unsigned short u16;
typedef __attribute__((ext_vector_type(8))) short bf16x8;
typedef __attribute__((ext_vector_type(4))) float f32x4;

#define S_LEN 2048
#define DM    2048
#define NH    16
#define HDIM  128

__device__ __forceinline__ u16 f2bf(float f) {
  union { float f; unsigned u; } v; v.f = f;
  unsigned r = v.u + 0x7fffu + ((v.u >> 16) & 1u);
  return (u16)(r >> 16);
}
__device__ __forceinline__ float bf2f(u16 h) {
  union { unsigned u; float f; } v; v.u = ((unsigned)h) << 16;
  return v.f;
}

typedef __attribute__((address_space(3))) void lds_void_t;
typedef const __attribute__((address_space(1))) void gbl_void_t;
__device__ __forceinline__ void gload_lds16(const void* g, void* l) {
  __builtin_amdgcn_global_load_lds((gbl_void_t*)g, (lds_void_t*)l, 16, 0, 0);
}

#define VMCNTN(nn) asm volatile("s_waitcnt vmcnt(%0)" :: "n"(nn) : "memory")

// ---------------------------------------------------------------- convert (5 tensors, one launch)
__global__ void cvt5_k(const float* s0, u16* d0, int n0,
                       const float* s1, u16* d1, int n1,
                       const float* s2, u16* d2, int n2,
                       const float* s3, u16* d3, int n3,
                       const float* s4, u16* d4, int n4) {
  const int stride = gridDim.x * blockDim.x;
  const int tid = blockIdx.x * blockDim.x + threadIdx.x;
#define CVT(S, D, N)                                        \
  for (int i = tid; i < ((N) >> 2); i += stride) {          \
    float4 v = ((const float4*)(S))[i];                     \
    ushort4 o;                                              \
    o.x = f2bf(v.x); o.y = f2bf(v.y);                       \
    o.z = f2bf(v.z); o.w = f2bf(v.w);                       \
    ((ushort4*)(D))[i] = o;                                 \
  }
  CVT(s0, d0, n0) CVT(s1, d1, n1) CVT(s2, d2, n2)
  CVT(s3, d3, n3) CVT(s4, d4, n4)
#undef CVT
}

// ---------------------------------------------------------------- 8-phase GEMM + T2 slot-swizzle  [R16 best: 316us total]
// MODE 0: plain store. MODE 1 (QKV): rope fused in epilogue -- each block's
// tile_n is entirely q, k, or v (BN=256 divides the 2048 z-boundary); rotary
// pairs are adjacent lanes (gcol=base+r0) so shfl_xor(acc,1) is the partner.
// q pre-scaled by log2e/sqrt(128) (exp2-folded flash softmax downstream).
template <int BM, int BN, int M, int N, int K, typename CT, int MODE>
__global__ __launch_bounds__(512, 2) void gemm8(const u16* __restrict__ A,
                                                const u16* __restrict__ Bm,
                                                CT* __restrict__ C,
                                                const float* __restrict__ fc,
                                                const float* __restrict__ fs,
                                                u16* __restrict__ qtp,
                                                u16* __restrict__ ktp) {
  constexpr int PWM = BM / 2, PWN = BN / 4;
  constexpr int MR = PWM / 16, NR = PWN / 16, NB = NR / 2;
  constexpr int LA = BM / 128, LB = BN / 128;
  constexpr int VM = LA + LB;
  constexpr int nbn = N / BN, nbm = M / BM;
  constexpr int nwg = nbm * nbn;                 // must be % 8 == 0
  constexpr int GM = 8;
  __shared__ u16 sA[4 * BM * 32];
  __shared__ u16 sB[4 * BN * 32];

  const int t = threadIdx.x;
  const int lane = t & 63, wid = t >> 6;
  const int r0 = lane & 15, kq = lane >> 4;
  const int wr = wid >> 2, wc = wid & 3;

  const int bid = blockIdx.x;
  const int wgl = (bid & 7) * (nwg >> 3) + (bid >> 3);  // XCD-contiguous
  const int gid = wgl / (GM * nbn);
  const int rem = wgl % (GM * nbn);
  const long tile_m = (long)(gid * GM + (rem & (GM - 1))) * BM;
  const long tile_n = (long)(rem >> 3) * BN;

  constexpr int NT = K >> 6;
  constexpr int NITER = NT >> 1;

  const int swzcol = ((t & 3) ^ ((t >> 3) & 3)) * 8;
  const u16* gA = A + (tile_m + (t >> 2)) * (long)K + swzcol;
  const u16* gB = Bm + (tile_n + (t >> 2)) * (long)K + swzcol;

  auto stageA = [&](int kt, int kh) {
    u16* base = &sA[((kt & 1) * 2 + kh) * (BM * 32)] + wid * 512;
#pragma unroll
    for (int r = 0; r < LA; ++r)
      gload_lds16(gA + (long)(r * 128) * K + kt * 64 + kh * 32, base + r * 4096);
  };
  auto stageB = [&](int kt, int kh) {
    u16* base = &sB[((kt & 1) * 2 + kh) * (BN * 32)] + wid * 512;
#pragma unroll
    for (int r = 0; r < LB; ++r)
      gload_lds16(gB + (long)(r * 128) * K + kt * 64 + kh * 32, base + r * 4096);
  };

  const int rdslot = (kq ^ ((r0 >> 1) & 3)) * 8;
  const int aoff = (wr * PWM + r0) * 32 + rdslot;
  const int boff = (wc * PWN + r0) * 32 + rdslot;

  f32x4 acc[MR][NR];
#pragma unroll
  for (int m = 0; m < MR; ++m)
#pragma unroll
    for (int n = 0; n < NR; ++n) acc[m][n] = (f32x4){0.f, 0.f, 0.f, 0.f};

  stageA(0, 0); stageB(0, 0); stageA(0, 1); stageB(0, 1);
  stageA(1, 0); stageB(1, 0);
  VMCNTN(VM);
  __builtin_amdgcn_s_barrier();

#define PH(KT, KH, G, STAGE_STMT, VM_STMT)                                  \
  {                                                                         \
    const u16* ra = &sA[(((KT) & 1) * 2 + (KH)) * (BM * 32)] + aoff;        \
    const u16* rb = &sB[(((KT) & 1) * 2 + (KH)) * (BN * 32)] + boff;        \
    if ((G) == 0) {                                                         \
      _Pragma("unroll") for (int m = 0; m < MR; ++m)                        \
          a[m] = *(const bf16x8*)(ra + m * 512);                            \
    }                                                                       \
    _Pragma("unroll") for (int n = 0; n < NB; ++n)                          \
        b[n] = *(const bf16x8*)(rb + ((G) * NB + n) * 512);                 \
    STAGE_STMT;                                                             \
    VM_STMT;                                                                \
    __builtin_amdgcn_s_barrier();                                           \
    __builtin_amdgcn_s_setprio(1);                                          \
    _Pragma("unroll") for (int m = 0; m < MR; ++m)                          \
        _Pragma("unroll") for (int n = 0; n < NB; ++n)                      \
            acc[m][(G) * NB + n] = __builtin_amdgcn_mfma_f32_16x16x32_bf16( \
                a[m], b[n], acc[m][(G) * NB + n], 0, 0, 0);                 \
    __builtin_amdgcn_s_setprio(0);                                          \
    __builtin_amdgcn_s_barrier();                                           \
  }

  for (int it = 0; it < NITER; ++it) {
    const int kt0 = 2 * it, kt1 = 2 * it + 1;
    const bool last = (it == NITER - 1);
    bf16x8 a[MR], b[NB];
    PH(kt0, 0, 0, stageA(kt1, 1), ((void)0));
    PH(kt0, 0, 1, stageB(kt1, 1), ((void)0));
    PH(kt0, 1, 0, { if (kt0 + 2 < NT) stageA(kt0 + 2, 0); }, ((void)0));
    PH(kt0, 1, 1, { if (kt0 + 2 < NT) stageB(kt0 + 2, 0); },
       { if (last) { VMCNTN(0); } else { VMCNTN(VM); } });
    PH(kt1, 0, 0, { if (kt0 + 2 < NT) stageA(kt0 + 2, 1); }, ((void)0));
    PH(kt1, 0, 1, { if (kt0 + 2 < NT) stageB(kt0 + 2, 1); }, ((void)0));
    PH(kt1, 1, 0, { if (kt0 + 3 < NT) stageA(kt0 + 3, 0); }, ((void)0));
    PH(kt1, 1, 1, { if (kt0 + 3 < NT) stageB(kt0 + 3, 0); }, VMCNTN(VM));
  }
#undef PH

  if constexpr (MODE == 1) {
    const int z = (int)(tile_n >> 11);         // 0=q 1=k 2=v (block-uniform)
    if (z == 2) {
#pragma unroll
      for (int m = 0; m < MR; ++m)
#pragma unroll
        for (int n = 0; n < NR; ++n)
#pragma unroll
          for (int r = 0; r < 4; ++r) {
            long grow = tile_m + wr * PWM + m * 16 + kq * 4 + r;
            long gcol = tile_n + wc * PWN + n * 16 + r0;
            C[grow * N + gcol] = (CT)f2bf(acc[m][n][r]);
          }
    } else {
      const float qsc = 0.12751743202f;        // log2(e)/sqrt(128)
#pragma unroll
      for (int m = 0; m < MR; ++m)
#pragma unroll
        for (int n = 0; n < NR; ++n)
#pragma unroll
          for (int r = 0; r < 4; ++r) {
            long grow = tile_m + wr * PWM + m * 16 + kq * 4 + r;
            long gcol = tile_n + wc * PWN + n * 16 + r0;
            int srow = (int)(grow & 2047), bidx = (int)(grow >> 11);
            int h = ((int)gcol >> 7) & 15, hd = (int)gcol & 127;
            float v = acc[m][n][r];
            float partner = __shfl_xor(v, 1);
            int hd2 = hd >> 1;
            float c = fc[srow * 64 + hd2], sn = fs[srow * 64 + hd2];
            float res = (r0 & 1) ? (partner * sn + v * c)
                                 : (v * c - partner * sn);
            if (z == 0) res *= qsc;
            u16* dst = z ? ktp : qtp;
            dst[((long)(bidx * 16 + h) * S_LEN + srow) * HDIM + hd] = f2bf(res);
          }
    }
  } else {
#pragma unroll
    for (int m = 0; m < MR; ++m)
#pragma unroll
      for (int n = 0; n < NR; ++n)
#pragma unroll
        for (int r = 0; r < 4; ++r) {
          long grow = tile_m + wr * PWM + m * 16 + kq * 4 + r;
          long gcol = tile_n + wc * PWN + n * 16 + r0;
          float v = acc[m][n][r];
          if constexpr (sizeof(CT) == 2) C[grow * N + gcol] = (CT)f2bf(v);
          else                           C[grow * N + gcol] = v;
        }
  }
}

// ---------------------------------------------------------------- V transpose -> (B,H,HD,S)
__global__ void vtrans_k(const u16* __restrict__ qkv, u16* __restrict__ vt) {
  __shared__ u16 tile[64][65];
  int bh = blockIdx.z;
  int b = bh >> 4, h = bh & 15;
  int s0 = blockIdx.x * 64, d0 = blockIdx.y * 64;
  int tx = threadIdx.x, ty = threadIdx.y;
#pragma unroll
  for (int i = 0; i < 64; i += 4) {
    int s = s0 + ty + i;
    tile[ty + i][tx] = qkv[((long)(b * S_LEN + s)) * 6144 + 4096 + h * HDIM + d0 + tx];
  }
  __syncthreads();
#pragma unroll
  for (int i = 0; i < 64; i += 4) {
    int d = d0 + ty + i;
    vt[((long)bh * HDIM + d) * S_LEN + s0 + tx] = tile[tx][ty + i];
  }
}

// ---------------------------------------------------------------- flash attention v8 (causal)  [R12 proven: 131us]
// grid (x=bh L2-local, y=tile heavy-first), 2 waves x 32 q-rows, KVBLK=32,
// explicit pipeline softmax(i)->QK(i+1)->prefetchK(i+2)->PV(i), exp2, cvt_pk.
__global__ __launch_bounds__(128) void flash_k(const u16* __restrict__ qt,
                                               const u16* __restrict__ kt,
                                               const u16* __restrict__ vt,
                                               u16* __restrict__ attn) {
  constexpr int PS = 40;
  __shared__ u16 pbuf[2][2][32 * PS]; // [parity][wid]
  const int t = threadIdx.x, lane = t & 63, wid = t >> 6;
  const int r0 = lane & 15, kq = lane >> 4;
  const int bh = blockIdx.x, b = bh >> 4, h = bh & 15;
  const int tile = (gridDim.y - 1) - blockIdx.y;   // heavy-first
  const int q0w = tile * 64 + wid * 32;
  const int crow = kq * 4;

  const u16* qb = qt + ((long)bh * S_LEN + q0w) * HDIM;
  const u16* kb = kt + (long)bh * S_LEN * HDIM;
  const u16* vb = vt + (long)bh * HDIM * S_LEN;
  u16* pb0 = &pbuf[0][wid][0];
  u16* pb1 = &pbuf[1][wid][0];

  bf16x8 aq[2][4];
#pragma unroll
  for (int qc = 0; qc < 2; ++qc)
#pragma unroll
    for (int kk = 0; kk < 4; ++kk)
      aq[qc][kk] = *(const bf16x8*)(qb + (qc * 16 + r0) * HDIM + kk * 32 + kq * 8);

  f32x4 o[2][8];
  float mrow[2] = {-1e30f, -1e30f}, lrow[2] = {0.f, 0.f};
#pragma unroll
  for (int qc = 0; qc < 2; ++qc)
#pragma unroll
    for (int dt = 0; dt < 8; ++dt) o[qc][dt] = (f32x4){0.f, 0.f, 0.f, 0.f};

  bf16x8 bkA[2][4], bkB[2][4], bvA[8], bvB[8];
  f32x4 saccA[2][2], saccB[2][2];

  auto loadK = [&](bf16x8 (&dst)[2][4], int kv) {
#pragma unroll
    for (int kc = 0; kc < 2; ++kc)
#pragma unroll
      for (int kk = 0; kk < 4; ++kk)
        dst[kc][kk] = *(const bf16x8*)(kb + (long)(kv + kc * 16 + r0) * HDIM + kk * 32 + kq * 8);
  };
  auto loadV = [&](bf16x8 (&dst)[8], int kv) {
#pragma unroll
    for (int dt = 0; dt < 8; ++dt)
      dst[dt] = *(const bf16x8*)(vb + (long)(dt * 16 + r0) * S_LEN + kv + kq * 8);
  };
  auto qk = [&](bf16x8 (&kf)[2][4], f32x4 (&sacc)[2][2]) {
    __builtin_amdgcn_s_setprio(1);
#pragma unroll
    for (int kc = 0; kc < 2; ++kc) {
      f32x4 a0 = (f32x4){0.f, 0.f, 0.f, 0.f};
      f32x4 a1 = (f32x4){0.f, 0.f, 0.f, 0.f};
#pragma unroll
      for (int kk = 0; kk < 4; ++kk) {
        a0 = __builtin_amdgcn_mfma_f32_16x16x32_bf16(kf[kc][kk], aq[0][kk], a0, 0, 0, 0);
        a1 = __builtin_amdgcn_mfma_f32_16x16x32_bf16(kf[kc][kk], aq[1][kk], a1, 0, 0, 0);
      }
      sacc[kc][0] = a0; sacc[kc][1] = a1;
    }
    __builtin_amdgcn_s_setprio(0);
  };
  auto softmax_store = [&](f32x4 (&sacc)[2][2], int kv0, u16* pb) {
    const bool diag = (kv0 == q0w);
#pragma unroll
    for (int qc = 0; qc < 2; ++qc) {
      float s[2][4];
#pragma unroll
      for (int kc = 0; kc < 2; ++kc)
#pragma unroll
        for (int r = 0; r < 4; ++r) {
          float v = sacc[kc][qc][r];
          if (diag && (kc * 16 + crow + r > qc * 16 + r0)) v = -1e30f;
          s[kc][r] = v;
        }
      float pm = fmaxf(fmaxf(fmaxf(s[0][0], s[0][1]), fmaxf(s[0][2], s[0][3])),
                       fmaxf(fmaxf(s[1][0], s[1][1]), fmaxf(s[1][2], s[1][3])));
      pm = fmaxf(pm, __shfl_xor(pm, 16));
      pm = fmaxf(pm, __shfl_xor(pm, 32));
      if (!__all(pm - mrow[qc] <= 11.5416f)) {   // defer-max (log2 units, e^8 bound)
        float mnew = fmaxf(mrow[qc], pm);
        float co = exp2f(mrow[qc] - mnew);
        mrow[qc] = mnew;
        lrow[qc] *= co;
        float cod[4];
#pragma unroll
        for (int r = 0; r < 4; ++r)
          cod[r] = __shfl(co, (lane & 48) | (crow + r));
#pragma unroll
        for (int dt = 0; dt < 8; ++dt)
#pragma unroll
          for (int r = 0; r < 4; ++r)
            o[qc][dt][r] *= cod[r];
      }
      float p[2][4];
      float rs = 0.f;
#pragma unroll
      for (int kc = 0; kc < 2; ++kc)
#pragma unroll
        for (int r = 0; r < 4; ++r) {
          p[kc][r] = exp2f(s[kc][r] - mrow[qc]);
          rs += p[kc][r];
        }
      rs += __shfl_xor(rs, 16);
      rs += __shfl_xor(rs, 32);
      lrow[qc] += rs;
#pragma unroll
      for (int kc = 0; kc < 2; ++kc) {
        unsigned w0, w1;
        asm("v_cvt_pk_bf16_f32 %0, %1, %2" : "=v"(w0) : "v"(p[kc][0]), "v"(p[kc][1]));
        asm("v_cvt_pk_bf16_f32 %0, %1, %2" : "=v"(w1) : "v"(p[kc][2]), "v"(p[kc][3]));
        uint2 w; w.x = w0; w.y = w1;
        *(uint2*)(pb + (qc * 16 + r0) * PS + kc * 16 + crow) = w;
      }
    }
  };
  auto pv = [&](const u16* pb, bf16x8 (&bv)[8]) {
    bf16x8 pa0 = *(const bf16x8*)(pb + r0 * PS + kq * 8);
    bf16x8 pa1 = *(const bf16x8*)(pb + (16 + r0) * PS + kq * 8);
    __builtin_amdgcn_s_setprio(1);
#pragma unroll
    for (int dt = 0; dt < 8; ++dt) {
      o[0][dt] = __builtin_amdgcn_mfma_f32_16x16x32_bf16(pa0, bv[dt], o[0][dt], 0, 0, 0);
      o[1][dt] = __builtin_amdgcn_mfma_f32_16x16x32_bf16(pa1, bv[dt], o[1][dt], 0, 0, 0);
    }
    __builtin_amdgcn_s_setprio(0);
  };

  loadK(bkA, 0);
  if (32 <= q0w) loadK(bkB, 32);
  qk(bkA, saccA);
  int kv0 = 0;
  for (;;) {
    {
      const bool more = (kv0 + 32 <= q0w);
      loadV(bvA, kv0);
      softmax_store(saccA, kv0, pb0);
      if (more) qk(bkB, saccB);
      if (kv0 + 64 <= q0w) loadK(bkA, kv0 + 64);
      pv(pb0, bvA);
      kv0 += 32;
      if (!more) break;
    }
    {
      const bool more = (kv0 + 32 <= q0w);
      loadV(bvB, kv0);
      softmax_store(saccB, kv0, pb1);
      if (more) qk(bkA, saccA);
      if (kv0 + 64 <= q0w) loadK(bkB, kv0 + 64);
      pv(pb1, bvB);
      kv0 += 32;
      if (!more) break;
    }
  }

#pragma unroll
  for (int qc = 0; qc < 2; ++qc) {
    float linv[4];
#pragma unroll
    for (int r = 0; r < 4; ++r)
      linv[r] = 1.0f / __shfl(lrow[qc], (lane & 48) | (crow + r));
#pragma unroll
    for (int dt = 0; dt < 8; ++dt)
#pragma unroll
      for (int r = 0; r < 4; ++r) {
        int srow = q0w + qc * 16 + crow + r;
        attn[((long)(b * S_LEN + srow)) * DM + h * HDIM + dt * 16 + r0] =
            f2bf(o[qc][dt][r] * linv[r]);
      }
  }
}

// ---------------------------------------------------------------- launch
extern "C" void kernel_launch(void* const* d_in, const int* in_sizes, int n_in,
                              void* d_out, int out_size, void* d_ws, size_t ws_size,
                              hipStream_t stream) {
  (void)in_sizes; (void)n_in; (void)out_size; (void)ws_size;
  const float* x  = (const float*)d_in[0];
  const float* fc = (const float*)d_in[2];
  const float* fs = (const float*)d_in[3];
  const float* wq = (const float*)d_in[5];
  const float* wk = (const float*)d_in[6];
  const float* wv = (const float*)d_in[7];
  const float* wo = (const float*)d_in[8];
  float* out = (float*)d_out;

  u16* xb   = (u16*)d_ws;            // 4096*2048
  u16* wqkv = xb + 8388608;          // 6144*2048
  u16* wob  = wqkv + 12582912;       // 2048*2048
  u16* qkv  = wob + 4194304;         // 4096*6144 (only v region written now)
  u16* qt   = qkv + 25165824;        // 32*2048*128
  u16* kt   = qt + 8388608;
  u16* vt   = kt + 8388608;
  u16* attn = qkv;                   // alias: v region dead after vtrans

  cvt5_k<<<2048, 256, 0, stream>>>(x, xb, 8388608,
                                   wq, wqkv, 4194304,
                                   wk, wqkv + 4194304, 4194304,
                                   wv, wqkv + 8388608, 4194304,
                                   wo, wob, 4194304);

  // QKV: M=4096 N=6144 K=2048, BM=128 -> 768 blocks = 3 rounds; rope fused
  gemm8<128, 256, 4096, 6144, 2048, u16, 1><<<768, 512, 0, stream>>>(
      xb, wqkv, qkv, fc, fs, qt, kt);

  vtrans_k<<<dim3(32, 2, 32), dim3(64, 4), 0, stream>>>(qkv, vt);

  // grid: x = bh (bh%8 per XCD -> per-XCD L2 K/V residency), y = tile heavy-first
  flash_k<<<dim3(32, 32), 128, 0, stream>>>(qt, kt, vt, attn);

  // OUT: M=4096 N=2048 K=2048, BM=128 -> 256 blocks = exactly 1 round
  gemm8<128, 256, 4096, 2048, 2048, float, 0><<<256, 512, 0, stream>>>(
      attn, wob, out, nullptr, nullptr, nullptr, nullptr);
}

// Round 22
// 288.555 us; speedup vs baseline: 1.1474x; 1.1002x over previous
//
#include <hip/hip_runtime.h>
#include <cstdint>

typedef unsigned short u16;
typedef __attribute__((ext_vector_type(8))) short bf16x8;
typedef __attribute__((ext_vector_type(4))) float f32x4;

#define S_LEN 2048
#define DM    2048
#define NH    16
#define HDIM  128

__device__ __forceinline__ u16 f2bf(float f) {
  union { float f; unsigned u; } v; v.f = f;
  unsigned r = v.u + 0x7fffu + ((v.u >> 16) & 1u);
  return (u16)(r >> 16);
}
__device__ __forceinline__ float bf2f(u16 h) {
  union { unsigned u; float f; } v; v.u = ((unsigned)h) << 16;
  return v.f;
}

typedef __attribute__((address_space(3))) void lds_void_t;
typedef const __attribute__((address_space(1))) void gbl_void_t;
__device__ __forceinline__ void gload_lds16(const void* g, void* l) {
  __builtin_amdgcn_global_load_lds((gbl_void_t*)g, (lds_void_t*)l, 16, 0, 0);
}

#define VMCNTN(nn) asm volatile("s_waitcnt vmcnt(%0)" :: "n"(nn) : "memory")

// ---------------------------------------------------------------- convert (5 tensors, one launch)
__global__ void cvt5_k(const float* s0, u16* d0, int n0,
                       const float* s1, u16* d1, int n1,
                       const float* s2, u16* d2, int n2,
                       const float* s3, u16* d3, int n3,
                       const float* s4, u16* d4, int n4) {
  const int stride = gridDim.x * blockDim.x;
  const int tid = blockIdx.x * blockDim.x + threadIdx.x;
#define CVT(S, D, N)                                        \
  for (int i = tid; i < ((N) >> 2); i += stride) {          \
    float4 v = ((const float4*)(S))[i];                     \
    ushort4 o;                                              \
    o.x = f2bf(v.x); o.y = f2bf(v.y);                       \
    o.z = f2bf(v.z); o.w = f2bf(v.w);                       \
    ((ushort4*)(D))[i] = o;                                 \
  }
  CVT(s0, d0, n0) CVT(s1, d1, n1) CVT(s2, d2, n2)
  CVT(s3, d3, n3) CVT(s4, d4, n4)
#undef CVT
}

// ---------------------------------------------------------------- 8-phase GEMM + T2 slot-swizzle
// MODE 0: plain store. MODE 1 (QKV): rope fused for q/k blocks; v blocks
// (z==2) transpose IN THE EPILOGUE via the (dead) staging LDS and write
// vt[(bh*HD+hd)*S + s] directly -- vtrans kernel deleted (was 32MB r/w +
// 16MB qkv write). Coalesced out: per col, 64 lanes b32 = 256B contiguous.
template <int BM, int BN, int M, int N, int K, typename CT, int MODE>
__global__ __launch_bounds__(512, 2) void gemm8(const u16* __restrict__ A,
                                                const u16* __restrict__ Bm,
                                                CT* __restrict__ C,
                                                const float* __restrict__ fc,
                                                const float* __restrict__ fs,
                                                u16* __restrict__ qtp,
                                                u16* __restrict__ ktp,
                                                u16* __restrict__ vtp) {
  constexpr int PWM = BM / 2, PWN = BN / 4;
  constexpr int MR = PWM / 16, NR = PWN / 16, NB = NR / 2;
  constexpr int LA = BM / 128, LB = BN / 128;
  constexpr int VM = LA + LB;
  constexpr int SASZ = 4 * BM * 32;
  constexpr int nbn = N / BN, nbm = M / BM;
  constexpr int nwg = nbm * nbn;                 // must be % 8 == 0
  constexpr int GM = 8;
  __shared__ u16 smem[SASZ + 4 * BN * 32];
  u16* sA = smem;
  u16* sB = smem + SASZ;

  const int t = threadIdx.x;
  const int lane = t & 63, wid = t >> 6;
  const int r0 = lane & 15, kq = lane >> 4;
  const int wr = wid >> 2, wc = wid & 3;

  const int bid = blockIdx.x;
  const int wgl = (bid & 7) * (nwg >> 3) + (bid >> 3);  // XCD-contiguous
  const int gid = wgl / (GM * nbn);
  const int rem = wgl % (GM * nbn);
  const long tile_m = (long)(gid * GM + (rem & (GM - 1))) * BM;
  const long tile_n = (long)(rem >> 3) * BN;

  constexpr int NT = K >> 6;
  constexpr int NITER = NT >> 1;

  const int swzcol = ((t & 3) ^ ((t >> 3) & 3)) * 8;
  const u16* gA = A + (tile_m + (t >> 2)) * (long)K + swzcol;
  const u16* gB = Bm + (tile_n + (t >> 2)) * (long)K + swzcol;

  auto stageA = [&](int kt, int kh) {
    u16* base = &sA[((kt & 1) * 2 + kh) * (BM * 32)] + wid * 512;
#pragma unroll
    for (int r = 0; r < LA; ++r)
      gload_lds16(gA + (long)(r * 128) * K + kt * 64 + kh * 32, base + r * 4096);
  };
  auto stageB = [&](int kt, int kh) {
    u16* base = &sB[((kt & 1) * 2 + kh) * (BN * 32)] + wid * 512;
#pragma unroll
    for (int r = 0; r < LB; ++r)
      gload_lds16(gB + (long)(r * 128) * K + kt * 64 + kh * 32, base + r * 4096);
  };

  const int rdslot = (kq ^ ((r0 >> 1) & 3)) * 8;
  const int aoff = (wr * PWM + r0) * 32 + rdslot;
  const int boff = (wc * PWN + r0) * 32 + rdslot;

  f32x4 acc[MR][NR];
#pragma unroll
  for (int m = 0; m < MR; ++m)
#pragma unroll
    for (int n = 0; n < NR; ++n) acc[m][n] = (f32x4){0.f, 0.f, 0.f, 0.f};

  stageA(0, 0); stageB(0, 0); stageA(0, 1); stageB(0, 1);
  stageA(1, 0); stageB(1, 0);
  VMCNTN(VM);
  __builtin_amdgcn_s_barrier();

#define PH(KT, KH, G, STAGE_STMT, VM_STMT)                                  \
  {                                                                         \
    const u16* ra = &sA[(((KT) & 1) * 2 + (KH)) * (BM * 32)] + aoff;        \
    const u16* rb = &sB[(((KT) & 1) * 2 + (KH)) * (BN * 32)] + boff;        \
    if ((G) == 0) {                                                         \
      _Pragma("unroll") for (int m = 0; m < MR; ++m)                        \
          a[m] = *(const bf16x8*)(ra + m * 512);                            \
    }                                                                       \
    _Pragma("unroll") for (int n = 0; n < NB; ++n)                          \
        b[n] = *(const bf16x8*)(rb + ((G) * NB + n) * 512);                 \
    STAGE_STMT;                                                             \
    VM_STMT;                                                                \
    __builtin_amdgcn_s_barrier();                                           \
    __builtin_amdgcn_s_setprio(1);                                          \
    _Pragma("unroll") for (int m = 0; m < MR; ++m)                          \
        _Pragma("unroll") for (int n = 0; n < NB; ++n)                      \
            acc[m][(G) * NB + n] = __builtin_amdgcn_mfma_f32_16x16x32_bf16( \
                a[m], b[n], acc[m][(G) * NB + n], 0, 0, 0);                 \
    __builtin_amdgcn_s_setprio(0);                                          \
    __builtin_amdgcn_s_barrier();                                           \
  }

  for (int it = 0; it < NITER; ++it) {
    const int kt0 = 2 * it, kt1 = 2 * it + 1;
    const bool last = (it == NITER - 1);
    bf16x8 a[MR], b[NB];
    PH(kt0, 0, 0, stageA(kt1, 1), ((void)0));
    PH(kt0, 0, 1, stageB(kt1, 1), ((void)0));
    PH(kt0, 1, 0, { if (kt0 + 2 < NT) stageA(kt0 + 2, 0); }, ((void)0));
    PH(kt0, 1, 1, { if (kt0 + 2 < NT) stageB(kt0 + 2, 0); },
       { if (last) { VMCNTN(0); } else { VMCNTN(VM); } });
    PH(kt1, 0, 0, { if (kt0 + 2 < NT) stageA(kt0 + 2, 1); }, ((void)0));
    PH(kt1, 0, 1, { if (kt0 + 2 < NT) stageB(kt0 + 2, 1); }, ((void)0));
    PH(kt1, 1, 0, { if (kt0 + 3 < NT) stageA(kt0 + 3, 0); }, ((void)0));
    PH(kt1, 1, 1, { if (kt0 + 3 < NT) stageB(kt0 + 3, 0); }, VMCNTN(VM));
  }
#undef PH

  if constexpr (MODE == 1) {
    const int z = (int)(tile_n >> 11);         // 0=q 1=k 2=v (block-uniform)
    if (z == 2) {
      // ---- fused V transpose: acc tile (128 s x 256 hd) -> vt[(bh,hd)][s]
      // tb stride 132 u16: write banks 2-4way transient; read 2 lanes/bank.
      u16* tb = smem;                          // staging LDS dead (loop ends w/ barrier)
#pragma unroll
      for (int m = 0; m < MR; ++m)
#pragma unroll
        for (int n = 0; n < NR; ++n) {
          int row0 = wr * PWM + m * 16 + kq * 4;
          int col  = wc * PWN + n * 16 + r0;
          ushort4 pk;
          pk.x = f2bf(acc[m][n][0]); pk.y = f2bf(acc[m][n][1]);
          pk.z = f2bf(acc[m][n][2]); pk.w = f2bf(acc[m][n][3]);
          *(ushort4*)(tb + col * 132 + row0) = pk;
        }
      __builtin_amdgcn_s_barrier();
      const int bidx = (int)(tile_m >> 11), s0 = (int)(tile_m & 2047);
#pragma unroll 4
      for (int it2 = 0; it2 < 32; ++it2) {
        int col = it2 * 8 + wid;               // 0..255
        long gc = tile_n + col;
        int h2 = ((int)gc >> 7) & 15, hd2 = (int)gc & 127;
        unsigned vv = *(const unsigned*)(tb + col * 132 + 2 * lane);
        *(unsigned*)(vtp + ((long)(bidx * 16 + h2) * HDIM + hd2) * S_LEN + s0 + 2 * lane) = vv;
      }
    } else {
      const float qsc = 0.12751743202f;        // log2(e)/sqrt(128)
#pragma unroll
      for (int m = 0; m < MR; ++m)
#pragma unroll
        for (int n = 0; n < NR; ++n)
#pragma unroll
          for (int r = 0; r < 4; ++r) {
            long grow = tile_m + wr * PWM + m * 16 + kq * 4 + r;
            long gcol = tile_n + wc * PWN + n * 16 + r0;
            int srow = (int)(grow & 2047), bidx = (int)(grow >> 11);
            int h = ((int)gcol >> 7) & 15, hd = (int)gcol & 127;
            float v = acc[m][n][r];
            float partner = __shfl_xor(v, 1);
            int hd2 = hd >> 1;
            float c = fc[srow * 64 + hd2], sn = fs[srow * 64 + hd2];
            float res = (r0 & 1) ? (partner * sn + v * c)
                                 : (v * c - partner * sn);
            if (z == 0) res *= qsc;
            u16* dst = z ? ktp : qtp;
            dst[((long)(bidx * 16 + h) * S_LEN + srow) * HDIM + hd] = f2bf(res);
          }
    }
  } else {
#pragma unroll
    for (int m = 0; m < MR; ++m)
#pragma unroll
      for (int n = 0; n < NR; ++n)
#pragma unroll
        for (int r = 0; r < 4; ++r) {
          long grow = tile_m + wr * PWM + m * 16 + kq * 4 + r;
          long gcol = tile_n + wc * PWN + n * 16 + r0;
          float v = acc[m][n][r];
          if constexpr (sizeof(CT) == 2) C[grow * N + gcol] = (CT)f2bf(v);
          else                           C[grow * N + gcol] = v;
        }
  }
}

// ---------------------------------------------------------------- flash attention v13 (causal)
// v8 + V-prefetch deepened one full step (named bvA/bvB alternate; V for
// step i+1 issues during step i, so a whole step covers its L2 latency).
__global__ __launch_bounds__(128) void flash_k(const u16* __restrict__ qt,
                                               const u16* __restrict__ kt,
                                               const u16* __restrict__ vt,
                                               u16* __restrict__ attn) {
  constexpr int PS = 40;
  __shared__ u16 pbuf[2][2][32 * PS]; // [parity][wid]
  const int t = threadIdx.x, lane = t & 63, wid = t >> 6;
  const int r0 = lane & 15, kq = lane >> 4;
  const int bh = blockIdx.x, b = bh >> 4, h = bh & 15;
  const int tile = (gridDim.y - 1) - blockIdx.y;   // heavy-first
  const int q0w = tile * 64 + wid * 32;
  const int crow = kq * 4;

  const u16* qb = qt + ((long)bh * S_LEN + q0w) * HDIM;
  const u16* kb = kt + (long)bh * S_LEN * HDIM;
  const u16* vb = vt + (long)bh * HDIM * S_LEN;
  u16* pb0 = &pbuf[0][wid][0];
  u16* pb1 = &pbuf[1][wid][0];

  bf16x8 aq[2][4];
#pragma unroll
  for (int qc = 0; qc < 2; ++qc)
#pragma unroll
    for (int kk = 0; kk < 4; ++kk)
      aq[qc][kk] = *(const bf16x8*)(qb + (qc * 16 + r0) * HDIM + kk * 32 + kq * 8);

  f32x4 o[2][8];
  float mrow[2] = {-1e30f, -1e30f}, lrow[2] = {0.f, 0.f};
#pragma unroll
  for (int qc = 0; qc < 2; ++qc)
#pragma unroll
    for (int dt = 0; dt < 8; ++dt) o[qc][dt] = (f32x4){0.f, 0.f, 0.f, 0.f};

  bf16x8 bkA[2][4], bkB[2][4], bvA[8], bvB[8];
  f32x4 saccA[2][2], saccB[2][2];

  auto loadK = [&](bf16x8 (&dst)[2][4], int kv) {
#pragma unroll
    for (int kc = 0; kc < 2; ++kc)
#pragma unroll
      for (int kk = 0; kk < 4; ++kk)
        dst[kc][kk] = *(const bf16x8*)(kb + (long)(kv + kc * 16 + r0) * HDIM + kk * 32 + kq * 8);
  };
  auto loadV = [&](bf16x8 (&dst)[8], int kv) {
#pragma unroll
    for (int dt = 0; dt < 8; ++dt)
      dst[dt] = *(const bf16x8*)(vb + (long)(dt * 16 + r0) * S_LEN + kv + kq * 8);
  };
  auto qk = [&](bf16x8 (&kf)[2][4], f32x4 (&sacc)[2][2]) {
    __builtin_amdgcn_s_setprio(1);
#pragma unroll
    for (int kc = 0; kc < 2; ++kc) {
      f32x4 a0 = (f32x4){0.f, 0.f, 0.f, 0.f};
      f32x4 a1 = (f32x4){0.f, 0.f, 0.f, 0.f};
#pragma unroll
      for (int kk = 0; kk < 4; ++kk) {
        a0 = __builtin_amdgcn_mfma_f32_16x16x32_bf16(kf[kc][kk], aq[0][kk], a0, 0, 0, 0);
        a1 = __builtin_amdgcn_mfma_f32_16x16x32_bf16(kf[kc][kk], aq[1][kk], a1, 0, 0, 0);
      }
      sacc[kc][0] = a0; sacc[kc][1] = a1;
    }
    __builtin_amdgcn_s_setprio(0);
  };
  auto softmax_store = [&](f32x4 (&sacc)[2][2], int kv0, u16* pb) {
    const bool diag = (kv0 == q0w);
#pragma unroll
    for (int qc = 0; qc < 2; ++qc) {
      float s[2][4];
#pragma unroll
      for (int kc = 0; kc < 2; ++kc)
#pragma unroll
        for (int r = 0; r < 4; ++r) {
          float v = sacc[kc][qc][r];
          if (diag && (kc * 16 + crow + r > qc * 16 + r0)) v = -1e30f;
          s[kc][r] = v;
        }
      float pm = fmaxf(fmaxf(fmaxf(s[0][0], s[0][1]), fmaxf(s[0][2], s[0][3])),
                       fmaxf(fmaxf(s[1][0], s[1][1]), fmaxf(s[1][2], s[1][3])));
      pm = fmaxf(pm, __shfl_xor(pm, 16));
      pm = fmaxf(pm, __shfl_xor(pm, 32));
      if (!__all(pm - mrow[qc] <= 11.5416f)) {   // defer-max (log2 units, e^8 bound)
        float mnew = fmaxf(mrow[qc], pm);
        float co = exp2f(mrow[qc] - mnew);
        mrow[qc] = mnew;
        lrow[qc] *= co;
        float cod[4];
#pragma unroll
        for (int r = 0; r < 4; ++r)
          cod[r] = __shfl(co, (lane & 48) | (crow + r));
#pragma unroll
        for (int dt = 0; dt < 8; ++dt)
#pragma unroll
          for (int r = 0; r < 4; ++r)
            o[qc][dt][r] *= cod[r];
      }
      float p[2][4];
      float rs = 0.f;
#pragma unroll
      for (int kc = 0; kc < 2; ++kc)
#pragma unroll
        for (int r = 0; r < 4; ++r) {
          p[kc][r] = exp2f(s[kc][r] - mrow[qc]);
          rs += p[kc][r];
        }
      rs += __shfl_xor(rs, 16);
      rs += __shfl_xor(rs, 32);
      lrow[qc] += rs;
#pragma unroll
      for (int kc = 0; kc < 2; ++kc) {
        unsigned w0, w1;
        asm("v_cvt_pk_bf16_f32 %0, %1, %2" : "=v"(w0) : "v"(p[kc][0]), "v"(p[kc][1]));
        asm("v_cvt_pk_bf16_f32 %0, %1, %2" : "=v"(w1) : "v"(p[kc][2]), "v"(p[kc][3]));
        uint2 w; w.x = w0; w.y = w1;
        *(uint2*)(pb + (qc * 16 + r0) * PS + kc * 16 + crow) = w;
      }
    }
  };
  auto pv = [&](const u16* pb, bf16x8 (&bv)[8]) {
    bf16x8 pa0 = *(const bf16x8*)(pb + r0 * PS + kq * 8);
    bf16x8 pa1 = *(const bf16x8*)(pb + (16 + r0) * PS + kq * 8);
    __builtin_amdgcn_s_setprio(1);
#pragma unroll
    for (int dt = 0; dt < 8; ++dt) {
      o[0][dt] = __builtin_amdgcn_mfma_f32_16x16x32_bf16(pa0, bv[dt], o[0][dt], 0, 0, 0);
      o[1][dt] = __builtin_amdgcn_mfma_f32_16x16x32_bf16(pa1, bv[dt], o[1][dt], 0, 0, 0);
    }
    __builtin_amdgcn_s_setprio(0);
  };

  loadK(bkA, 0);
  if (32 <= q0w) loadK(bkB, 32);
  loadV(bvA, 0);
  qk(bkA, saccA);
  int kv0 = 0;
  for (;;) {
    {
      const bool more = (kv0 + 32 <= q0w);
      if (more) loadV(bvB, kv0 + 32);      // V for NEXT step (full-step cover)
      softmax_store(saccA, kv0, pb0);
      if (more) qk(bkB, saccB);
      if (kv0 + 64 <= q0w) loadK(bkA, kv0 + 64);
      pv(pb0, bvA);
      kv0 += 32;
      if (!more) break;
    }
    {
      const bool more = (kv0 + 32 <= q0w);
      if (more) loadV(bvA, kv0 + 32);
      softmax_store(saccB, kv0, pb1);
      if (more) qk(bkA, saccA);
      if (kv0 + 64 <= q0w) loadK(bkB, kv0 + 64);
      pv(pb1, bvB);
      kv0 += 32;
      if (!more) break;
    }
  }

#pragma unroll
  for (int qc = 0; qc < 2; ++qc) {
    float linv[4];
#pragma unroll
    for (int r = 0; r < 4; ++r)
      linv[r] = 1.0f / __shfl(lrow[qc], (lane & 48) | (crow + r));
#pragma unroll
    for (int dt = 0; dt < 8; ++dt)
#pragma unroll
      for (int r = 0; r < 4; ++r) {
        int srow = q0w + qc * 16 + crow + r;
        attn[((long)(b * S_LEN + srow)) * DM + h * HDIM + dt * 16 + r0] =
            f2bf(o[qc][dt][r] * linv[r]);
      }
  }
}

// ---------------------------------------------------------------- launch
extern "C" void kernel_launch(void* const* d_in, const int* in_sizes, int n_in,
                              void* d_out, int out_size, void* d_ws, size_t ws_size,
                              hipStream_t stream) {
  (void)in_sizes; (void)n_in; (void)out_size; (void)ws_size;
  const float* x  = (const float*)d_in[0];
  const float* fc = (const float*)d_in[2];
  const float* fs = (const float*)d_in[3];
  const float* wq = (const float*)d_in[5];
  const float* wk = (const float*)d_in[6];
  const float* wv = (const float*)d_in[7];
  const float* wo = (const float*)d_in[8];
  float* out = (float*)d_out;

  u16* xb   = (u16*)d_ws;            // 4096*2048
  u16* wqkv = xb + 8388608;          // 6144*2048
  u16* wob  = wqkv + 12582912;       // 2048*2048
  u16* qkv  = wob + 4194304;         // 4096*6144 (unused except attn alias)
  u16* qt   = qkv + 25165824;        // 32*2048*128
  u16* kt   = qt + 8388608;
  u16* vt   = kt + 8388608;
  u16* attn = qkv;                   // alias

  cvt5_k<<<2048, 256, 0, stream>>>(x, xb, 8388608,
                                   wq, wqkv, 4194304,
                                   wk, wqkv + 4194304, 4194304,
                                   wv, wqkv + 8388608, 4194304,
                                   wo, wob, 4194304);

  // QKV: rope fused (q/k), V transposed in-epilogue (vtrans deleted)
  gemm8<128, 256, 4096, 6144, 2048, u16, 1><<<768, 512, 0, stream>>>(
      xb, wqkv, qkv, fc, fs, qt, kt, vt);

  // grid: x = bh (bh%8 per XCD -> per-XCD L2 K/V residency), y = tile heavy-first
  flash_k<<<dim3(32, 32), 128, 0, stream>>>(qt, kt, vt, attn);

  // OUT: M=4096 N=2048 K=2048, BM=128 -> 256 blocks = exactly 1 round
  gemm8<128, 256, 4096, 2048, 2048, float, 0><<<256, 512, 0, stream>>>(
      attn, wob, out, nullptr, nullptr, nullptr, nullptr, nullptr);
}